// Round 6
// baseline (388.251 us; speedup 1.0000x reference)
//
#include <hip/hip_runtime.h>
#include <hip/hip_bf16.h>

// 16-qubit statevector sim, batch 64. idx bit p ("pos p") of state index; wire w <-> pos 15-w.
// All CRX fused into ctrl-selected 1q gates {M0,M1}; all gates are register-bit gates; LDS
// remaps rotate which 4 positions live in registers. Intermediate full state is packed bf16
// (re|im in one uint), transposed: saddr = [pos4..15 -> bits0..11][pos0..3 -> bits12..15].
// L0 tail folded into T2[pos3][pos4][pos0..2]: full = T2 * pre(pos4..15) (12-bit L0 state).
// R15: SINGLE kernel pF2 (1024 blk x 256 thr). Phase 1 = R14's pB2 (prep + L0 + T2-fold Gx
//   + L1 w0..w11, store st). Then per-BATCH device barrier: the 16 blocks of batch b
//   (dispatch-contiguous, all 1024 blocks co-resident at 4 blk/CU) arrive on ctr[b]
//   (release: per-thread __threadfence + atomicAdd; acquire: ATOMIC_ACQUIRE spin + fence).
//   Phase 2 = old p3 re-mapped to 16 blk x 256 thr/batch: block bits = pos11..14 (mp),
//   lane = pos4..8 + pos15(bit5), wv = pos9,10; gates w12..15 + CRX15 read from LDS Ps
//   (global P eliminated); |amp|^2 + PauliZ sums; 16th arriver (ctr2) does FC+log_softmax.
//   feats/ctr/ctr2 zeroed by hipMemsetAsync before launch. Batches pipeline through the
//   barrier (early batches start phase 2 while later ones finish phase 1).

#define DIM 65536
#define BATCH 64
#define PSTR 580   // per-block floats in Ps: 512 matrices + 64 T2 + crx_c + crx_s (+pad)

// ---------------- gate helpers ----------------

template<int RB>
__device__ __forceinline__ void g1q_reg(float* sr, float* si, const float* U) {
  float u00r=U[0],u00i=U[1],u01r=U[2],u01i=U[3],u10r=U[4],u10i=U[5],u11r=U[6],u11i=U[7];
#pragma unroll
  for (int k = 0; k < 8; ++k) {
    int lo = k & ((1<<RB)-1);
    int j0 = ((k >> RB) << (RB+1)) | lo;
    int j1 = j0 | (1<<RB);
    float a0r=sr[j0], a0i=si[j0], a1r=sr[j1], a1i=si[j1];
    sr[j0] = u00r*a0r - u00i*a0i + u01r*a1r - u01i*a1i;
    si[j0] = u00r*a0i + u00i*a0r + u01r*a1i + u01i*a1r;
    sr[j1] = u10r*a0r - u10i*a0i + u11r*a1r - u11i*a1i;
    si[j1] = u10r*a0i + u10i*a0r + u11r*a1i + u11i*a1r;
  }
}

template<int RB, int CB>
__device__ __forceinline__ void gsel_reg_cc(float* sr, float* si, const float* M0, const float* M1) {
  float a0=M0[0],a1=M0[1],a2=M0[2],a3=M0[3],a4=M0[4],a5=M0[5],a6=M0[6],a7=M0[7];
  float b0=M1[0],b1=M1[1],b2=M1[2],b3=M1[3],b4=M1[4],b5=M1[5],b6=M1[6],b7=M1[7];
#pragma unroll
  for (int k = 0; k < 8; ++k) {
    int lo = k & ((1<<RB)-1);
    int j0 = ((k >> RB) << (RB+1)) | lo;
    int j1 = j0 | (1<<RB);
    const bool c = ((j0 >> CB) & 1) != 0;   // compile-time per k
    float u00r=c?b0:a0, u00i=c?b1:a1, u01r=c?b2:a2, u01i=c?b3:a3;
    float u10r=c?b4:a4, u10i=c?b5:a5, u11r=c?b6:a6, u11i=c?b7:a7;
    float p0r=sr[j0], p0i=si[j0], p1r=sr[j1], p1i=si[j1];
    sr[j0] = u00r*p0r - u00i*p0i + u01r*p1r - u01i*p1i;
    si[j0] = u00r*p0i + u00i*p0r + u01r*p1i + u01i*p1r;
    sr[j1] = u10r*p0r - u10i*p0i + u11r*p1r - u11i*p1i;
    si[j1] = u10r*p0i + u10i*p0r + u11r*p1i + u11i*p1r;
  }
}

template<int RB>
__device__ __forceinline__ void gsel_reg_pred(float* sr, float* si, const float* M0,
                                              const float* M1, bool ctrl) {
  float u[8];
#pragma unroll
  for (int e = 0; e < 8; ++e) u[e] = ctrl ? M1[e] : M0[e];
  g1q_reg<RB>(sr, si, u);
}

template<int CB, int LB>
__device__ __forceinline__ void crx_reg_lane(float* sr, float* si, float c, float s) {
#pragma unroll
  for (int k = 0; k < 8; ++k) {
    int lo2 = k & ((1<<CB)-1);
    int j = ((((k >> CB) << (CB+1)) | lo2)) | (1<<CB);
    float pr = __shfl_xor(sr[j], 1<<LB, 64);
    float pi = __shfl_xor(si[j], 1<<LB, 64);
    float mr = sr[j], mi = si[j];
    sr[j] = c*mr + s*pi;
    si[j] = c*mi - s*pr;
  }
}

__device__ __forceinline__ int swz(int o) { return o ^ ((o>>4)&15) ^ ((o>>8)&15); }

// packed bf16 complex: re in low 16, im in high 16 (RNE rounding)
__device__ __forceinline__ unsigned bfp(float r, float i) {
  unsigned ur = __float_as_uint(r), ui = __float_as_uint(i);
  ur = (ur + 0x7fffu + ((ur >> 16) & 1u)) >> 16;
  ui = (ui + 0x7fffu + ((ui >> 16) & 1u)) & 0xffff0000u;
  return (ur & 0xffffu) | ui;
}
__device__ __forceinline__ float bfr(unsigned u) { return __uint_as_float(u << 16); }
__device__ __forceinline__ float bfi(unsigned u) { return __uint_as_float(u & 0xffff0000u); }

#define MP(Pb, l, q, s) ((Pb) + (((l)*16+(q))*2+(s))*8)

// ---------------- pF2: fused pipeline with per-batch device barrier ----------------
// Phase 1 (tile = pos4..15, block mp = pos0..3):
// S1/LA: reg=i8..11; S1 lanes l0..5=i2..7, wv=i0,1; LA lanes l0..5=i0..5, wv=i6,7.
// S2/LB: reg=i4..7, l0..3=i8..11, l4,5=i2,3, wv=i0,1.  S3/LC: reg=i0..3, l0..5=i4..9, wv=i10,11.
// pre canonical: paddr = [i8..11 -> bits0..3][i0..7 -> bits4..11].
// Phase 2 (block mp = pos11..14): reg = pos0..3, lane0..4 = pos4..8, lane5 = pos15,
// wv = pos9,10; saddr base = (lane&31) | wv<<5 | (mp>>3)<<7 | (mp&7)<<8 | (lane>>5)<<11.

__global__ __launch_bounds__(256) void pF2(unsigned* __restrict__ st,
                                           const float* __restrict__ x, const float* __restrict__ w0,
                                           const float* __restrict__ x0, const float* __restrict__ w1,
                                           const float* __restrict__ x1,
                                           const float* __restrict__ fcw, const float* __restrict__ fcb,
                                           float* __restrict__ out, float* __restrict__ feats,
                                           int* __restrict__ ctr, int* __restrict__ ctr2) {
  __shared__ float2 lds2[4096];   // 32 KB shared scratch (remaps, pre; phase-2 reduction)
  __shared__ float Ps[PSTR];      // per-block gate tables
  __shared__ int flagS2;
  int blk = blockIdx.x;
  int b = blk >> 4, mp = blk & 15;
  int t = threadIdx.x, lane = t & 63, wv = t >> 6;   // wv in 0..3

  // ---- prep: gate tables into Ps (every block, for its batch) ----
  {
    float (*su)[8] = reinterpret_cast<float(*)[8]>(lds2);
    if (t < 32) {
      int l = t >> 4, q = t & 15;
      const float* W = (l ? w1 : w0) + q*3;
      float xa = 0.5f * x[b*16 + q];
      float cr = cosf(xa), sx = sinf(xa);
      float phi = W[0], th = W[1], om = W[2];
      float ct = cosf(0.5f*th), stt = sinf(0.5f*th);
      float po = 0.5f*(phi+om), pm = 0.5f*(phi-om);
      float ar =  cosf(po)*ct,  ai = -sinf(po)*ct;
      float br = -cosf(pm)*stt, bi = -sinf(pm)*stt;
      float cr2 = cosf(pm)*stt, ci2 = -sinf(pm)*stt;
      float dr =  cosf(po)*ct,  di =  sinf(po)*ct;
      float U[8];
      U[0] = ar*cr + bi*sx;   U[1] = ai*cr - br*sx;
      U[2] = ai*sx + br*cr;   U[3] = -ar*sx + bi*cr;
      U[4] = cr2*cr + di*sx;  U[5] = ci2*cr - dr*sx;
      U[6] = ci2*sx + dr*cr;  U[7] = -cr2*sx + di*cr;
      float* M0 = MP(Ps, l, q, 0);
      float* M1 = M0 + 8;
#pragma unroll
      for (int e = 0; e < 8; ++e) { M0[e] = U[e]; su[t][e] = U[e]; }
      if (q == 0) {
        float ang = l ? 0.5f*x0[15] : 0.f;           // boundary: M1 = U * RX
        float cg = cosf(ang), sg = sinf(ang);
        M1[0] =  cg*U[0] + sg*U[3];  M1[1] = cg*U[1] - sg*U[2];
        M1[2] =  sg*U[1] + cg*U[2];  M1[3] = -sg*U[0] + cg*U[3];
        M1[4] =  cg*U[4] + sg*U[7];  M1[5] = cg*U[5] - sg*U[6];
        M1[6] =  sg*U[5] + cg*U[6];  M1[7] = -sg*U[4] + cg*U[7];
      } else {
        float ang = 0.5f*(l ? x1[q-1] : x0[q-1]);    // within layer: M1 = RX * U
        float cg = cosf(ang), sg = sinf(ang);
        M1[0] = cg*U[0] + sg*U[5];  M1[1] = cg*U[1] - sg*U[4];
        M1[2] = cg*U[2] + sg*U[7];  M1[3] = cg*U[3] - sg*U[6];
        M1[4] = cg*U[4] + sg*U[1];  M1[5] = cg*U[5] - sg*U[0];
        M1[6] = cg*U[6] + sg*U[3];  M1[7] = cg*U[7] - sg*U[2];
      }
      if (t == 0) { Ps[576] = cosf(0.5f*x1[15]); Ps[577] = sinf(0.5f*x1[15]); }
    }
    __syncthreads();   // B0: Ps matrices + su ready
  }

  // ---- L0: S1 (t==0, sparse) ∥ T2 tail (wave 1, lanes 0..7) ----
  float sr[16], si[16];
#pragma unroll
  for (int r = 0; r < 16; ++r) { sr[r] = 0.f; si[r] = 0.f; }
  if (t == 0) {
    sr[0] = 1.f;
    g1q_reg<3>(sr, si, MP(Ps,0,0,0));
    gsel_reg_cc<2,3>(sr, si, MP(Ps,0,1,0), MP(Ps,0,1,1));
    gsel_reg_cc<1,2>(sr, si, MP(Ps,0,2,0), MP(Ps,0,2,1));
    gsel_reg_cc<0,1>(sr, si, MP(Ps,0,3,0), MP(Ps,0,3,1));
  } else if (t >= 64 && t < 72) {
    // oldT chain (F13,F14,F15 col-0 products + CRX w12,w13,w14) parallel over k=0..7.
    float (*su)[8] = reinterpret_cast<float(*)[8]>(lds2);
    int k = t - 64;
    float xr = su[13][((k>>2)&1)*4], xi = su[13][((k>>2)&1)*4+1];
    float yr = su[14][((k>>1)&1)*4], yi = su[14][((k>>1)&1)*4+1];
    float zr = su[15][(k&1)*4],      zi = su[15][(k&1)*4+1];
    float pr = xr*yr - xi*yi, pi = xr*yi + xi*yr;
    float T0r = pr*zr - pi*zi, T0i = pr*zi + pi*zr;
    float a12 = 0.5f*x0[12], c12 = cosf(a12), s12 = sinf(a12);
    float T0r4 = __shfl_xor(T0r, 4, 64), T0i4 = __shfl_xor(T0i, 4, 64);
    float T1r = c12*T0r + s12*T0i4, T1i = c12*T0i - s12*T0r4;
    float a13 = 0.5f*x0[13], c13 = cosf(a13), s13 = sinf(a13);
    float T0r2 = __shfl_xor(T0r, 2, 64), T0i2 = __shfl_xor(T0i, 2, 64);
    float T1r2 = __shfl_xor(T1r, 2, 64), T1i2 = __shfl_xor(T1i, 2, 64);
    float n0r, n0i, n1r, n1i;
    if (k & 4) {
      n0r = c13*T0r + s13*T0i2; n0i = c13*T0i - s13*T0r2;
      n1r = c13*T1r + s13*T1i2; n1i = c13*T1i - s13*T1r2;
    } else { n0r = T0r; n0i = T0i; n1r = T1r; n1i = T1i; }
    float a14 = 0.5f*x0[14], c14 = cosf(a14), s14 = sinf(a14);
    float n0r1 = __shfl_xor(n0r, 1, 64), n0i1 = __shfl_xor(n0i, 1, 64);
    float n1r1 = __shfl_xor(n1r, 1, 64), n1i1 = __shfl_xor(n1i, 1, 64);
    float F0r, F0i, F1r, F1i;
    if (k & 2) {
      F0r = c14*n0r + s14*n0i1; F0i = c14*n0i - s14*n0r1;
      F1r = c14*n1r + s14*n1i1; F1i = c14*n1i - s14*n1r1;
    } else { F0r = n0r; F0i = n0i; F1r = n1r; F1i = n1i; }
    const float* A = MP(Ps,0,12,0);
    const float* B = MP(Ps,0,12,1);
    float* T2 = Ps + 512;
#pragma unroll
    for (int j0 = 0; j0 < 2; ++j0) {
      float tr = j0 ? F1r : F0r, ti = j0 ? F1i : F0i;
#pragma unroll
      for (int j1 = 0; j1 < 2; ++j1) {
        const float* Wm = j1 ? B : A;
        float fr = Wm[j0*4], fi = Wm[j0*4+1];
        T2[((j0*2 + j1)*8 + k)*2 + 0] = tr*fr - ti*fi;
        T2[((j0*2 + j1)*8 + k)*2 + 1] = tr*fi + ti*fr;
      }
    }
  }
  __syncthreads();   // B1: T2 done, su dead, S1 regs ready

  // S1-layout store: o = i0,1(wv) | i2..7(lane)<<2 | i8..11(r)<<8
#pragma unroll
  for (int r = 0; r < 16; ++r) {
    int o = wv | (lane << 2) | (r << 8);
    lds2[swz(o)] = make_float2(sr[r], si[r]);
  }
  __syncthreads();   // B2
  // S2-layout read
#pragma unroll
  for (int r = 0; r < 16; ++r) {
    int o = wv | (((lane>>4)&3) << 2) | (r << 4) | ((lane&15) << 8);
    float2 v = lds2[swz(o)]; sr[r] = v.x; si[r] = v.y;
  }
  // S2 support: t<16 only; others hold exact zeros.
  if (t < 16) {
    gsel_reg_pred<3>(sr, si, MP(Ps,0,4,0), MP(Ps,0,4,1), (lane&1)!=0);
    gsel_reg_cc<2,3>(sr, si, MP(Ps,0,5,0), MP(Ps,0,5,1));
    gsel_reg_cc<1,2>(sr, si, MP(Ps,0,6,0), MP(Ps,0,6,1));
    gsel_reg_cc<0,1>(sr, si, MP(Ps,0,7,0), MP(Ps,0,7,1));
  }
#pragma unroll
  for (int r = 0; r < 16; ++r) {
    int o = wv | (((lane>>4)&3) << 2) | (r << 4) | ((lane&15) << 8);
    lds2[swz(o)] = make_float2(sr[r], si[r]);
  }
  __syncthreads();   // B3
  // S3-layout read
#pragma unroll
  for (int r = 0; r < 16; ++r) {
    int o = r | (lane << 4) | (wv << 10);
    float2 v = lds2[swz(o)]; sr[r] = v.x; si[r] = v.y;
  }
  // S3: w8..w11 — dense, all 256 threads
  gsel_reg_pred<3>(sr, si, MP(Ps,0,8,0), MP(Ps,0,8,1), (lane&1)!=0);
  gsel_reg_cc<2,3>(sr, si, MP(Ps,0,9,0), MP(Ps,0,9,1));
  gsel_reg_cc<1,2>(sr, si, MP(Ps,0,10,0), MP(Ps,0,10,1));
  gsel_reg_cc<0,1>(sr, si, MP(Ps,0,11,0), MP(Ps,0,11,1));
  __syncthreads();   // B4
  // pre store: paddr = [i8..11 -> bits0..3][i0..7 -> bits4..11]
#pragma unroll
  for (int r = 0; r < 16; ++r) {
    int paddr = ((lane>>4)&3) | (wv << 2) | (r << 4) | ((lane&15) << 8);
    lds2[swz(paddr)] = make_float2(sr[r], si[r]);
  }
  __syncthreads();   // B5

  // ---- L1: LA read (pre canonical), Gx with T2 factor folded, w1..w11 ----
  {
#pragma unroll
    for (int r = 0; r < 16; ++r) {
      int paddr = r | (lane << 4) | (wv << 10);
      float2 v = lds2[swz(paddr)]; sr[r] = v.x; si[r] = v.y;
    }
    int k = mp & 7;
    const float* tf = Ps + 512 + (((((mp>>3)&1)*2 + (lane&1))*8 + k)*2);
    float fr = tf[0], fi = tf[1];
    const float* M = (mp&1) ? MP(Ps,1,0,1) : MP(Ps,1,0,0);  // Gx ctrl pos0 = mp&1 (uniform)
    float v8[8];
#pragma unroll
    for (int e = 0; e < 4; ++e) {
      v8[2*e]   = fr*M[2*e]   - fi*M[2*e+1];
      v8[2*e+1] = fr*M[2*e+1] + fi*M[2*e];
    }
    g1q_reg<3>(sr, si, v8);   // Gx (L1 w0, tgt pos15=reg3) with factor folded
  }
  gsel_reg_cc<2,3>(sr, si, MP(Ps,1,1,0), MP(Ps,1,1,1));
  gsel_reg_cc<1,2>(sr, si, MP(Ps,1,2,0), MP(Ps,1,2,1));
  gsel_reg_cc<0,1>(sr, si, MP(Ps,1,3,0), MP(Ps,1,3,1));
  __syncthreads();   // B6
  // LA-layout store
#pragma unroll
  for (int r = 0; r < 16; ++r) {
    int o = lane | (wv << 6) | (r << 8);
    lds2[swz(o)] = make_float2(sr[r], si[r]);
  }
  __syncthreads();   // B7
  // LB read (S2 canonical)
#pragma unroll
  for (int r = 0; r < 16; ++r) {
    int o = wv | (((lane>>4)&3) << 2) | (r << 4) | ((lane&15) << 8);
    float2 v = lds2[swz(o)]; sr[r] = v.x; si[r] = v.y;
  }
  gsel_reg_pred<3>(sr, si, MP(Ps,1,4,0), MP(Ps,1,4,1), (lane&1)!=0);
  gsel_reg_cc<2,3>(sr, si, MP(Ps,1,5,0), MP(Ps,1,5,1));
  gsel_reg_cc<1,2>(sr, si, MP(Ps,1,6,0), MP(Ps,1,6,1));
  gsel_reg_cc<0,1>(sr, si, MP(Ps,1,7,0), MP(Ps,1,7,1));
#pragma unroll
  for (int r = 0; r < 16; ++r) {
    int o = wv | (((lane>>4)&3) << 2) | (r << 4) | ((lane&15) << 8);
    lds2[swz(o)] = make_float2(sr[r], si[r]);
  }
  __syncthreads();   // B8
  // LC read (S3 canonical)
#pragma unroll
  for (int r = 0; r < 16; ++r) {
    int o = r | (lane << 4) | (wv << 10);
    float2 v = lds2[swz(o)]; sr[r] = v.x; si[r] = v.y;
  }
  gsel_reg_pred<3>(sr, si, MP(Ps,1,8,0), MP(Ps,1,8,1), (lane&1)!=0);
  gsel_reg_cc<2,3>(sr, si, MP(Ps,1,9,0), MP(Ps,1,9,1));
  gsel_reg_cc<1,2>(sr, si, MP(Ps,1,10,0), MP(Ps,1,10,1));
  gsel_reg_cc<0,1>(sr, si, MP(Ps,1,11,0), MP(Ps,1,11,1));
  // store packed: saddr0..3 = reg (pos4..7) -> 16 contiguous uints = 4x uint4
  {
    int sbase = (lane << 4) | (wv << 10) | (mp << 12);
    uint4* dst = (uint4*)(st + (size_t)b*DIM + sbase);
#pragma unroll
    for (int g = 0; g < 4; ++g)
      dst[g] = make_uint4(bfp(sr[4*g],si[4*g]), bfp(sr[4*g+1],si[4*g+1]),
                          bfp(sr[4*g+2],si[4*g+2]), bfp(sr[4*g+3],si[4*g+3]));
  }

  // ---- per-batch device barrier: 16 blocks of batch b sync on ctr[b] ----
  __threadfence();   // release: this thread's st stores visible agent-wide (wbl2)
  __syncthreads();   // all threads in block have fenced
  if (t == 0) {
    atomicAdd(&ctr[b], 1);
    while (__hip_atomic_load(&ctr[b], __ATOMIC_ACQUIRE, __HIP_MEMORY_SCOPE_AGENT) < 16)
      __builtin_amdgcn_s_sleep(4);
  }
  __syncthreads();
  __threadfence();   // acquire for all threads (invalidate stale lines)

  // ---- phase 2: L1 w12..15 + CRX15, observables, 16th-arriver FC ----
  {
    // block bits: pos12..14 = mp&7, pos11 = mp>>3. lane: pos4..8 = lane&31, pos15 = lane>>5.
    // wv: pos9,10. reg = pos0..3 (saddr bits 12..15).
    int base = (lane&31) | (wv << 5) | (((mp>>3)&1) << 7) | ((mp&7) << 8) | ((lane>>5) << 11);
    const unsigned* S = st + (size_t)b*DIM + base;
#pragma unroll
    for (int r = 0; r < 16; ++r) { unsigned u = S[r << 12]; sr[r] = bfr(u); si[r] = bfi(u); }

    gsel_reg_pred<3>(sr, si, MP(Ps,1,12,0), MP(Ps,1,12,1), (lane&1)!=0);
    gsel_reg_cc<2,3>(sr, si, MP(Ps,1,13,0), MP(Ps,1,13,1));
    gsel_reg_cc<1,2>(sr, si, MP(Ps,1,14,0), MP(Ps,1,14,1));
    gsel_reg_cc<0,1>(sr, si, MP(Ps,1,15,0), MP(Ps,1,15,1));
    crx_reg_lane<0,5>(sr, si, Ps[576], Ps[577]);

    float tot=0.f, sA=0.f, sB=0.f, sC=0.f, sD=0.f;
#pragma unroll
    for (int r = 0; r < 16; ++r) {
      float p = sr[r]*sr[r] + si[r]*si[r];
      tot += p;
      sA += (r & 1) ? -p : p;   // pos0 -> wire15
      sB += (r & 2) ? -p : p;   // pos1 -> wire14
      sC += (r & 4) ? -p : p;   // pos2 -> wire13
      sD += (r & 8) ? -p : p;   // pos3 -> wire12
    }
    float f[16];
    f[15] = sA; f[14] = sB; f[13] = sC; f[12] = sD;
    f[11] = (lane&1)  ? -tot : tot;   // pos4
    f[10] = (lane&2)  ? -tot : tot;   // pos5
    f[9]  = (lane&4)  ? -tot : tot;   // pos6
    f[8]  = (lane&8)  ? -tot : tot;   // pos7
    f[7]  = (lane&16) ? -tot : tot;   // pos8
    f[0]  = (lane&32) ? -tot : tot;   // pos15
    f[6]  = (wv&1)    ? -tot : tot;   // pos9
    f[5]  = (wv&2)    ? -tot : tot;   // pos10
    f[4]  = (mp&8)    ? -tot : tot;   // pos11
    f[3]  = (mp&1)    ? -tot : tot;   // pos12
    f[2]  = (mp&2)    ? -tot : tot;   // pos13
    f[1]  = (mp&4)    ? -tot : tot;   // pos14
#pragma unroll
    for (int w = 0; w < 16; ++w) {
#pragma unroll
      for (int off = 32; off; off >>= 1) f[w] += __shfl_xor(f[w], off, 64);
    }
    float* shm = (float*)lds2;   // scratch dead; alias for reductions
    if (lane == 0) {
#pragma unroll
      for (int w = 0; w < 16; ++w) shm[wv*17 + w] = f[w];
    }
    __syncthreads();
    if (t < 16) {
      float acc = 0.f;
#pragma unroll
      for (int i = 0; i < 4; ++i) acc += shm[i*17 + t];
      atomicAdd(&feats[b*16 + t], acc);
    }

    // last block per batch computes FC + log_softmax
    __syncthreads();
    if (t == 0) { __threadfence(); flagS2 = atomicAdd(&ctr2[b], 1); }
    __syncthreads();
    if (flagS2 == 15) {
      float* fs = shm + 96;
      float* lg = shm + 128;
      if (t < 16) fs[t] = __hip_atomic_load(&feats[b*16 + t], __ATOMIC_RELAXED, __HIP_MEMORY_SCOPE_AGENT);
      __syncthreads();
      if (t < 23) {
        float acc = fcb[t];
#pragma unroll
        for (int w = 0; w < 16; ++w) acc += fs[w] * fcw[t*16 + w];
        lg[t] = acc;
      }
      __syncthreads();
      if (t < 23) {
        float mx = -1e30f;
#pragma unroll
        for (int j = 0; j < 23; ++j) mx = fmaxf(mx, lg[j]);
        float Ssum = 0.f;
#pragma unroll
        for (int j = 0; j < 23; ++j) Ssum += expf(lg[j] - mx);
        out[b*23 + t] = lg[t] - mx - logf(Ssum);
      }
    }
  }
}

extern "C" void kernel_launch(void* const* d_in, const int* in_sizes, int n_in,
                              void* d_out, int out_size, void* d_ws, size_t ws_size,
                              hipStream_t stream) {
  const float* x   = (const float*)d_in[0];
  const float* w0  = (const float*)d_in[1];
  const float* x0  = (const float*)d_in[2];
  const float* w1  = (const float*)d_in[3];
  const float* x1  = (const float*)d_in[4];
  const float* fcw = (const float*)d_in[5];
  const float* fcb = (const float*)d_in[6];
  float* out = (float*)d_out;

  char* ws = (char*)d_ws;
  unsigned* st  = (unsigned*)ws;                                   // 16 MB
  float*  feats = (float*)(ws + (size_t)BATCH * DIM * 4);          // 64*16 f32
  int*    ctr   = (int*)(feats + BATCH*16);                        // 64 int (barrier)
  int*    ctr2  = ctr + BATCH;                                     // 64 int (FC arrival)

  hipMemsetAsync(feats, 0, BATCH*16*sizeof(float) + 2*BATCH*sizeof(int), stream);
  pF2<<<1024, 256, 0, stream>>>(st, x, w0, x0, w1, x1, fcw, fcb, out, feats, ctr, ctr2);
  (void)in_sizes; (void)n_in; (void)out_size; (void)ws_size;
}

// Round 7
// 122.406 us; speedup vs baseline: 3.1718x; 3.1718x over previous
//
#include <hip/hip_runtime.h>
#include <hip/hip_bf16.h>

// 16-qubit statevector sim, batch 64. idx bit p ("pos p") of state index; wire w <-> pos 15-w.
// All CRX fused into ctrl-selected 1q gates {M0,M1}; all gates are register-bit gates; LDS
// remaps rotate which 4 positions live in registers. Intermediate full state is packed bf16
// (re|im in one uint), transposed: saddr = [pos4..15 -> bits0..11][pos0..3 -> bits12..15].
// L0 tail folded into T2[pos3][pos4][pos0..2]: full = T2 * pre(pos4..15) (12-bit L0 state).
// R16 = R14 two-kernel structure (R6's fused per-batch barrier serialized into generations:
//   grid==capacity left no backfill -> 325us; reverted) + sparse-L0 handoffs:
//   - S1->S2: t0 writes 16 live amps to slots swz(r<<8); t<16 read 1 each. (slot 0 is in the
//     su region but su[0] is dead; T2 wave reads only su[13..15] = slots 52..63.)
//   - S2->S3: t<16 write 16 slots swz(r<<4|t<<8) (= old store-back addrs); ALL threads read
//     their reg0 slot swz(lane<<4|wv<<10) (same o algebraically), rezero regs 1..15.
//   - S1/S2/S3 gates sparse: live j0 = multiples of 2^(RB+1) -> 1+2+4+8 butterflies vs 32.
//     Skipped butterflies are exact 0->0 (bit-identical result).
//   Saves ~46 LDS ops/thread, 1 barrier (9->8), ~250 VALU/thread. L1 + p3 unchanged.
//   pB2 = 1024 blk x 256 thr (block = b, mp=pos0..3; tile = pos4..15, 16 regs/thread).
//   p3  = 512 blk x 512 thr: L1 w12..15 + CRX15, |amp|^2 + PauliZ sums, 8th-arriver FC.

#define DIM 65536
#define BATCH 64
#define PSTR 580   // per-batch floats in P/Ps: 512 matrices + 64 T2 + crx_c + crx_s (+pad)

// ---------------- gate helpers (dense) ----------------

template<int RB>
__device__ __forceinline__ void g1q_reg(float* sr, float* si, const float* U) {
  float u00r=U[0],u00i=U[1],u01r=U[2],u01i=U[3],u10r=U[4],u10i=U[5],u11r=U[6],u11i=U[7];
#pragma unroll
  for (int k = 0; k < 8; ++k) {
    int lo = k & ((1<<RB)-1);
    int j0 = ((k >> RB) << (RB+1)) | lo;
    int j1 = j0 | (1<<RB);
    float a0r=sr[j0], a0i=si[j0], a1r=sr[j1], a1i=si[j1];
    sr[j0] = u00r*a0r - u00i*a0i + u01r*a1r - u01i*a1i;
    si[j0] = u00r*a0i + u00i*a0r + u01r*a1i + u01i*a1r;
    sr[j1] = u10r*a0r - u10i*a0i + u11r*a1r - u11i*a1i;
    si[j1] = u10r*a0i + u10i*a0r + u11r*a1i + u11i*a1r;
  }
}

template<int RB, int CB>
__device__ __forceinline__ void gsel_reg_cc(float* sr, float* si, const float* M0, const float* M1) {
  float a0=M0[0],a1=M0[1],a2=M0[2],a3=M0[3],a4=M0[4],a5=M0[5],a6=M0[6],a7=M0[7];
  float b0=M1[0],b1=M1[1],b2=M1[2],b3=M1[3],b4=M1[4],b5=M1[5],b6=M1[6],b7=M1[7];
#pragma unroll
  for (int k = 0; k < 8; ++k) {
    int lo = k & ((1<<RB)-1);
    int j0 = ((k >> RB) << (RB+1)) | lo;
    int j1 = j0 | (1<<RB);
    const bool c = ((j0 >> CB) & 1) != 0;   // compile-time per k
    float u00r=c?b0:a0, u00i=c?b1:a1, u01r=c?b2:a2, u01i=c?b3:a3;
    float u10r=c?b4:a4, u10i=c?b5:a5, u11r=c?b6:a6, u11i=c?b7:a7;
    float p0r=sr[j0], p0i=si[j0], p1r=sr[j1], p1i=si[j1];
    sr[j0] = u00r*p0r - u00i*p0i + u01r*p1r - u01i*p1i;
    si[j0] = u00r*p0i + u00i*p0r + u01r*p1i + u01i*p1r;
    sr[j1] = u10r*p0r - u10i*p0i + u11r*p1r - u11i*p1i;
    si[j1] = u10r*p0i + u10i*p0r + u11r*p1i + u11i*p1r;
  }
}

template<int RB>
__device__ __forceinline__ void gsel_reg_pred(float* sr, float* si, const float* M0,
                                              const float* M1, bool ctrl) {
  float u[8];
#pragma unroll
  for (int e = 0; e < 8; ++e) u[e] = ctrl ? M1[e] : M0[e];
  g1q_reg<RB>(sr, si, u);
}

// ---------------- gate helpers (sparse: live j0 = multiples of 2^(RB+1)) ----------------
// Valid when all live amps have target bit AND all lower previously-targeted bits following
// the S1/S2/S3 gate cadence: before gate RB, live regs = multiples of 2<<RB. Skipped pairs
// are exact zeros (0->0), so results are bit-identical to the dense version.

template<int RB>
__device__ __forceinline__ void g1q_sp(float* sr, float* si, const float* U) {
  float u00r=U[0],u00i=U[1],u01r=U[2],u01i=U[3],u10r=U[4],u10i=U[5],u11r=U[6],u11i=U[7];
#pragma unroll
  for (int m = 0; m < (8>>RB); ++m) {
    int j0 = m << (RB+1);
    int j1 = j0 | (1<<RB);
    float a0r=sr[j0], a0i=si[j0], a1r=sr[j1], a1i=si[j1];
    sr[j0] = u00r*a0r - u00i*a0i + u01r*a1r - u01i*a1i;
    si[j0] = u00r*a0i + u00i*a0r + u01r*a1i + u01i*a1r;
    sr[j1] = u10r*a0r - u10i*a0i + u11r*a1r - u11i*a1i;
    si[j1] = u10r*a0i + u10i*a0r + u11r*a1i + u11i*a1r;
  }
}

template<int RB, int CB>
__device__ __forceinline__ void gsel_sp(float* sr, float* si, const float* M0, const float* M1) {
  float a0=M0[0],a1=M0[1],a2=M0[2],a3=M0[3],a4=M0[4],a5=M0[5],a6=M0[6],a7=M0[7];
  float b0=M1[0],b1=M1[1],b2=M1[2],b3=M1[3],b4=M1[4],b5=M1[5],b6=M1[6],b7=M1[7];
#pragma unroll
  for (int m = 0; m < (8>>RB); ++m) {
    int j0 = m << (RB+1);
    int j1 = j0 | (1<<RB);
    const bool c = ((j0 >> CB) & 1) != 0;
    float u00r=c?b0:a0, u00i=c?b1:a1, u01r=c?b2:a2, u01i=c?b3:a3;
    float u10r=c?b4:a4, u10i=c?b5:a5, u11r=c?b6:a6, u11i=c?b7:a7;
    float p0r=sr[j0], p0i=si[j0], p1r=sr[j1], p1i=si[j1];
    sr[j0] = u00r*p0r - u00i*p0i + u01r*p1r - u01i*p1i;
    si[j0] = u00r*p0i + u00i*p0r + u01r*p1i + u01i*p1r;
    sr[j1] = u10r*p0r - u10i*p0i + u11r*p1r - u11i*p1i;
    si[j1] = u10r*p0i + u10i*p0r + u11r*p1i + u11i*p1r;
  }
}

template<int RB>
__device__ __forceinline__ void gsel_pred_sp(float* sr, float* si, const float* M0,
                                             const float* M1, bool ctrl) {
  float u[8];
#pragma unroll
  for (int e = 0; e < 8; ++e) u[e] = ctrl ? M1[e] : M0[e];
  g1q_sp<RB>(sr, si, u);
}

template<int CB, int LB>
__device__ __forceinline__ void crx_reg_lane(float* sr, float* si, float c, float s) {
#pragma unroll
  for (int k = 0; k < 8; ++k) {
    int lo2 = k & ((1<<CB)-1);
    int j = ((((k >> CB) << (CB+1)) | lo2)) | (1<<CB);
    float pr = __shfl_xor(sr[j], 1<<LB, 64);
    float pi = __shfl_xor(si[j], 1<<LB, 64);
    float mr = sr[j], mi = si[j];
    sr[j] = c*mr + s*pi;
    si[j] = c*mi - s*pr;
  }
}

__device__ __forceinline__ int swz(int o) { return o ^ ((o>>4)&15) ^ ((o>>8)&15); }

// packed bf16 complex: re in low 16, im in high 16 (RNE rounding)
__device__ __forceinline__ unsigned bfp(float r, float i) {
  unsigned ur = __float_as_uint(r), ui = __float_as_uint(i);
  ur = (ur + 0x7fffu + ((ur >> 16) & 1u)) >> 16;
  ui = (ui + 0x7fffu + ((ui >> 16) & 1u)) & 0xffff0000u;
  return (ur & 0xffffu) | ui;
}
__device__ __forceinline__ float bfr(unsigned u) { return __uint_as_float(u << 16); }
__device__ __forceinline__ float bfi(unsigned u) { return __uint_as_float(u & 0xffff0000u); }

#define MP(Pb, l, q, s) ((Pb) + (((l)*16+(q))*2+(s))*8)

// ---------------- pB2: prep + sparse L0 + T2-fold Gx + L1 w1..w11 ----------------
// i_k = pos_{k+4} (12-bit tile index). Canonical scratch addr o = sum i_j << j (swz'd).
// S2/LB layout: reg=i4..7, l0..3=i8..11, l4,5=i2,3, wv=i0,1.
// S3/LC layout: reg=i0..3, l0..5=i4..9, wv=i10,11.  LA: reg=i8..11, l0..5=i0..5, wv=i6,7.
// pre canonical: paddr = [i8..11 -> bits0..3][i0..7 -> bits4..11].
// L1: Gx (w0) tgt pos15=reg3 ctrl pos0=mp&1 (uniform); w4 ctrl pos12=l0; w8 ctrl pos8=l0.
// Store saddr = (lane<<4)|(wv<<10)|(mp<<12) + reg.

__global__ __launch_bounds__(256) void pB2(unsigned* __restrict__ st,
                                           const float* __restrict__ x, const float* __restrict__ w0,
                                           const float* __restrict__ x0, const float* __restrict__ w1,
                                           const float* __restrict__ x1, float* __restrict__ P,
                                           float* __restrict__ feats, int* __restrict__ ctr) {
  __shared__ float2 lds2[4096];   // 32 KB shared scratch (remaps, pre)
  __shared__ float Ps[PSTR];      // per-block gate tables (same layout as global P)
  int blk = blockIdx.x;
  int b = blk >> 4, mp = blk & 15;
  int t = threadIdx.x, lane = t & 63, wv = t >> 6;   // wv in 0..3

  // ---- prep: gate tables into Ps (every block, for its batch) ----
  {
    float (*su)[8] = reinterpret_cast<float(*)[8]>(lds2);
    if (mp == 0 && t < 16) feats[b*16 + t] = 0.f;
    if (mp == 0 && t == 16) ctr[b] = 0;
    if (t < 32) {
      int l = t >> 4, q = t & 15;
      const float* W = (l ? w1 : w0) + q*3;
      float xa = 0.5f * x[b*16 + q];
      float cr = cosf(xa), sx = sinf(xa);
      float phi = W[0], th = W[1], om = W[2];
      float ct = cosf(0.5f*th), stt = sinf(0.5f*th);
      float po = 0.5f*(phi+om), pm = 0.5f*(phi-om);
      float ar =  cosf(po)*ct,  ai = -sinf(po)*ct;
      float br = -cosf(pm)*stt, bi = -sinf(pm)*stt;
      float cr2 = cosf(pm)*stt, ci2 = -sinf(pm)*stt;
      float dr =  cosf(po)*ct,  di =  sinf(po)*ct;
      float U[8];
      U[0] = ar*cr + bi*sx;   U[1] = ai*cr - br*sx;
      U[2] = ai*sx + br*cr;   U[3] = -ar*sx + bi*cr;
      U[4] = cr2*cr + di*sx;  U[5] = ci2*cr - dr*sx;
      U[6] = ci2*sx + dr*cr;  U[7] = -cr2*sx + di*cr;
      float* M0 = MP(Ps, l, q, 0);
      float* M1 = M0 + 8;
#pragma unroll
      for (int e = 0; e < 8; ++e) { M0[e] = U[e]; su[t][e] = U[e]; }
      if (q == 0) {
        float ang = l ? 0.5f*x0[15] : 0.f;           // boundary: M1 = U * RX
        float cg = cosf(ang), sg = sinf(ang);
        M1[0] =  cg*U[0] + sg*U[3];  M1[1] = cg*U[1] - sg*U[2];
        M1[2] =  sg*U[1] + cg*U[2];  M1[3] = -sg*U[0] + cg*U[3];
        M1[4] =  cg*U[4] + sg*U[7];  M1[5] = cg*U[5] - sg*U[6];
        M1[6] =  sg*U[5] + cg*U[6];  M1[7] = -sg*U[4] + cg*U[7];
      } else {
        float ang = 0.5f*(l ? x1[q-1] : x0[q-1]);    // within layer: M1 = RX * U
        float cg = cosf(ang), sg = sinf(ang);
        M1[0] = cg*U[0] + sg*U[5];  M1[1] = cg*U[1] - sg*U[4];
        M1[2] = cg*U[2] + sg*U[7];  M1[3] = cg*U[3] - sg*U[6];
        M1[4] = cg*U[4] + sg*U[1];  M1[5] = cg*U[5] - sg*U[0];
        M1[6] = cg*U[6] + sg*U[3];  M1[7] = cg*U[7] - sg*U[2];
      }
      if (t == 0) { Ps[576] = cosf(0.5f*x1[15]); Ps[577] = sinf(0.5f*x1[15]); }
    }
    __syncthreads();   // B0: Ps matrices + su ready
  }

  // ---- L0: S1 sparse (t==0) + handoff ∥ T2 tail (wave 1, lanes 0..7) ----
  float sr[16], si[16];
  if (t == 0) {
#pragma unroll
    for (int r = 0; r < 16; ++r) { sr[r] = 0.f; si[r] = 0.f; }
    sr[0] = 1.f;
    // S1 sparse: w0..w3 (tgt i11..i8 = reg3..0); live = {0} -> {0,8} -> ... -> all 16.
    g1q_sp<3>(sr, si, MP(Ps,0,0,0));
    gsel_sp<2,3>(sr, si, MP(Ps,0,1,0), MP(Ps,0,1,1));
    gsel_sp<1,2>(sr, si, MP(Ps,0,2,0), MP(Ps,0,2,1));
    gsel_sp<0,1>(sr, si, MP(Ps,0,3,0), MP(Ps,0,3,1));
    // handoff: amp(i8..11=r) -> S2 owner thread r, its reg0 slot = swz(r<<8) = (r<<8)|r.
    // Only slot 0 lies in the su region (su[0], dead); T2 reads su[13..15] = slots 52..63.
#pragma unroll
    for (int r = 0; r < 16; ++r) lds2[swz(r << 8)] = make_float2(sr[r], si[r]);
  } else if (t >= 64 && t < 72) {
    // oldT chain (F13,F14,F15 col-0 products + CRX w12,w13,w14) parallel over k=0..7.
    float (*su)[8] = reinterpret_cast<float(*)[8]>(lds2);
    int k = t - 64;
    float xr = su[13][((k>>2)&1)*4], xi = su[13][((k>>2)&1)*4+1];
    float yr = su[14][((k>>1)&1)*4], yi = su[14][((k>>1)&1)*4+1];
    float zr = su[15][(k&1)*4],      zi = su[15][(k&1)*4+1];
    float pr = xr*yr - xi*yi, pi = xr*yi + xi*yr;
    float T0r = pr*zr - pi*zi, T0i = pr*zi + pi*zr;
    float a12 = 0.5f*x0[12], c12 = cosf(a12), s12 = sinf(a12);
    float T0r4 = __shfl_xor(T0r, 4, 64), T0i4 = __shfl_xor(T0i, 4, 64);
    float T1r = c12*T0r + s12*T0i4, T1i = c12*T0i - s12*T0r4;
    float a13 = 0.5f*x0[13], c13 = cosf(a13), s13 = sinf(a13);
    float T0r2 = __shfl_xor(T0r, 2, 64), T0i2 = __shfl_xor(T0i, 2, 64);
    float T1r2 = __shfl_xor(T1r, 2, 64), T1i2 = __shfl_xor(T1i, 2, 64);
    float n0r, n0i, n1r, n1i;
    if (k & 4) {
      n0r = c13*T0r + s13*T0i2; n0i = c13*T0i - s13*T0r2;
      n1r = c13*T1r + s13*T1i2; n1i = c13*T1i - s13*T1r2;
    } else { n0r = T0r; n0i = T0i; n1r = T1r; n1i = T1i; }
    float a14 = 0.5f*x0[14], c14 = cosf(a14), s14 = sinf(a14);
    float n0r1 = __shfl_xor(n0r, 1, 64), n0i1 = __shfl_xor(n0i, 1, 64);
    float n1r1 = __shfl_xor(n1r, 1, 64), n1i1 = __shfl_xor(n1i, 1, 64);
    float F0r, F0i, F1r, F1i;
    if (k & 2) {
      F0r = c14*n0r + s14*n0i1; F0i = c14*n0i - s14*n0r1;
      F1r = c14*n1r + s14*n1i1; F1i = c14*n1i - s14*n1r1;
    } else { F0r = n0r; F0i = n0i; F1r = n1r; F1i = n1i; }
    const float* A = MP(Ps,0,12,0);
    const float* B = MP(Ps,0,12,1);
    float* T2 = Ps + 512;
#pragma unroll
    for (int j0 = 0; j0 < 2; ++j0) {
      float tr = j0 ? F1r : F0r, ti = j0 ? F1i : F0i;
#pragma unroll
      for (int j1 = 0; j1 < 2; ++j1) {
        const float* Wm = j1 ? B : A;
        float fr = Wm[j0*4], fi = Wm[j0*4+1];
        T2[((j0*2 + j1)*8 + k)*2 + 0] = tr*fr - ti*fi;
        T2[((j0*2 + j1)*8 + k)*2 + 1] = tr*fi + ti*fr;
      }
    }
  }
  if (mp == 0) {   // publish the P subset p3 reads (L1 w12..15 matrices + crx15 c/s)
    if (t >= 192) P[(size_t)b*PSTR + 256 + t] = Ps[256 + t];       // 448..511
    else if (t == 1) { P[(size_t)b*PSTR + 576] = Ps[576]; P[(size_t)b*PSTR + 577] = Ps[577]; }
  }
  __syncthreads();   // B1: t0 handoff + T2 done, su dead

  // ---- S2 sparse (t<16): read 1 amp, gates, write 16 slots ----
  if (t < 16) {
    float2 v = lds2[swz(t << 8)];
    sr[0] = v.x; si[0] = v.y;
#pragma unroll
    for (int r = 1; r < 16; ++r) { sr[r] = 0.f; si[r] = 0.f; }   // t0's 1..15 were handed off
    // w4 (tgt i7=reg3, ctrl i8=l0=t&1), w5..w7 (reg2..0); live {0}->...->all 16.
    gsel_pred_sp<3>(sr, si, MP(Ps,0,4,0), MP(Ps,0,4,1), (t&1)!=0);
    gsel_sp<2,3>(sr, si, MP(Ps,0,5,0), MP(Ps,0,5,1));
    gsel_sp<1,2>(sr, si, MP(Ps,0,6,0), MP(Ps,0,6,1));
    gsel_sp<0,1>(sr, si, MP(Ps,0,7,0), MP(Ps,0,7,1));
    // handoff: amp(i4..7=r, i8..11=t) -> S3 owner reads slot swz(r<<4 | t<<8).
    // r=0 slot = own S1 handoff slot (already consumed) -> no cross-thread clobber.
#pragma unroll
    for (int r = 0; r < 16; ++r)
      lds2[swz((r << 4) | (t << 8))] = make_float2(sr[r], si[r]);
  }
  __syncthreads();   // B2: S2 handoff slots ready

  // ---- S3 sparse (all 256 threads): read 1 amp, gates ----
  {
    // S3 layout reg0 slot: o = 0 | lane<<4 | wv<<10  (= r<<4|t'<<8 of the writer)
    float2 v = lds2[swz((lane << 4) | (wv << 10))];
    sr[0] = v.x; si[0] = v.y;
#pragma unroll
    for (int r = 1; r < 16; ++r) { sr[r] = 0.f; si[r] = 0.f; }
  }
  __syncthreads();   // B3: all handoff reads done before pre-store overwrites scratch
  // w8 (tgt i3=reg3, ctrl i4=l0), w9..w11 (reg2..0); live {0}->...->all 16.
  gsel_pred_sp<3>(sr, si, MP(Ps,0,8,0), MP(Ps,0,8,1), (lane&1)!=0);
  gsel_sp<2,3>(sr, si, MP(Ps,0,9,0), MP(Ps,0,9,1));
  gsel_sp<1,2>(sr, si, MP(Ps,0,10,0), MP(Ps,0,10,1));
  gsel_sp<0,1>(sr, si, MP(Ps,0,11,0), MP(Ps,0,11,1));
  // pre store: paddr = [i8..11 -> bits0..3][i0..7 -> bits4..11]
#pragma unroll
  for (int r = 0; r < 16; ++r) {
    int paddr = ((lane>>4)&3) | (wv << 2) | (r << 4) | ((lane&15) << 8);
    lds2[swz(paddr)] = make_float2(sr[r], si[r]);
  }
  __syncthreads();   // B4: pre complete

  // ---- L1: LA read (pre canonical), Gx with T2 factor folded, w1..w11 ----
  {
    // LA: reg=i8..11 (pos12..15), l0..5=i0..5 (pos4..9), wv=i6,7 (pos10,11)
#pragma unroll
    for (int r = 0; r < 16; ++r) {
      int paddr = r | (lane << 4) | (wv << 10);
      float2 v = lds2[swz(paddr)]; sr[r] = v.x; si[r] = v.y;
    }
    // T2 factor: pos0,1,2 = mp&7 (k), pos3 = mp>>3 (j0), pos4 = lane&1 (j1) — fold into Gx
    int k = mp & 7;
    const float* tf = Ps + 512 + (((((mp>>3)&1)*2 + (lane&1))*8 + k)*2);
    float fr = tf[0], fi = tf[1];
    const float* M = (mp&1) ? MP(Ps,1,0,1) : MP(Ps,1,0,0);  // Gx ctrl pos0 = mp&1 (uniform)
    float v8[8];
#pragma unroll
    for (int e = 0; e < 4; ++e) {
      v8[2*e]   = fr*M[2*e]   - fi*M[2*e+1];
      v8[2*e+1] = fr*M[2*e+1] + fi*M[2*e];
    }
    g1q_reg<3>(sr, si, v8);   // Gx (L1 w0, tgt pos15=reg3) with factor folded
  }
  gsel_reg_cc<2,3>(sr, si, MP(Ps,1,1,0), MP(Ps,1,1,1));
  gsel_reg_cc<1,2>(sr, si, MP(Ps,1,2,0), MP(Ps,1,2,1));
  gsel_reg_cc<0,1>(sr, si, MP(Ps,1,3,0), MP(Ps,1,3,1));
  __syncthreads();   // B5: all pre reads done before LA store overwrites scratch
  // LA-layout store: o = i0..5(lane) | i6,7(wv)<<6 | i8..11(r)<<8
#pragma unroll
  for (int r = 0; r < 16; ++r) {
    int o = lane | (wv << 6) | (r << 8);
    lds2[swz(o)] = make_float2(sr[r], si[r]);
  }
  __syncthreads();   // B6
  // LB read (S2 canonical): reg=i4..7 (pos8..11), l0..3=i8..11 (pos12..15), l4,5=i2,3, wv=i0,1
#pragma unroll
  for (int r = 0; r < 16; ++r) {
    int o = wv | (((lane>>4)&3) << 2) | (r << 4) | ((lane&15) << 8);
    float2 v = lds2[swz(o)]; sr[r] = v.x; si[r] = v.y;
  }
  // LB: w4 (tgt pos11=reg3, ctrl pos12=l0), w5..w7 (tgt pos10..8)
  gsel_reg_pred<3>(sr, si, MP(Ps,1,4,0), MP(Ps,1,4,1), (lane&1)!=0);
  gsel_reg_cc<2,3>(sr, si, MP(Ps,1,5,0), MP(Ps,1,5,1));
  gsel_reg_cc<1,2>(sr, si, MP(Ps,1,6,0), MP(Ps,1,6,1));
  gsel_reg_cc<0,1>(sr, si, MP(Ps,1,7,0), MP(Ps,1,7,1));
  // store back at own addresses (no cross-thread hazard)
#pragma unroll
  for (int r = 0; r < 16; ++r) {
    int o = wv | (((lane>>4)&3) << 2) | (r << 4) | ((lane&15) << 8);
    lds2[swz(o)] = make_float2(sr[r], si[r]);
  }
  __syncthreads();   // B7
  // LC read (S3 canonical): reg=i0..3 (pos4..7), l0..5=i4..9 (pos8..13), wv=i10,11 (pos14,15)
#pragma unroll
  for (int r = 0; r < 16; ++r) {
    int o = r | (lane << 4) | (wv << 10);
    float2 v = lds2[swz(o)]; sr[r] = v.x; si[r] = v.y;
  }
  // LC: w8 (tgt pos7=reg3, ctrl pos8=l0), w9..w11 (tgt pos6..4)
  gsel_reg_pred<3>(sr, si, MP(Ps,1,8,0), MP(Ps,1,8,1), (lane&1)!=0);
  gsel_reg_cc<2,3>(sr, si, MP(Ps,1,9,0), MP(Ps,1,9,1));
  gsel_reg_cc<1,2>(sr, si, MP(Ps,1,10,0), MP(Ps,1,10,1));
  gsel_reg_cc<0,1>(sr, si, MP(Ps,1,11,0), MP(Ps,1,11,1));
  // store packed: saddr0..3 = reg (pos4..7) -> 16 contiguous uints = 4x uint4
  {
    int sbase = (lane << 4) | (wv << 10) | (mp << 12);
    uint4* dst = (uint4*)(st + (size_t)b*DIM + sbase);
#pragma unroll
    for (int g = 0; g < 4; ++g)
      dst[g] = make_uint4(bfp(sr[4*g],si[4*g]), bfp(sr[4*g+1],si[4*g+1]),
                          bfp(sr[4*g+2],si[4*g+2]), bfp(sr[4*g+3],si[4*g+3]));
  }
}

// ---------------- p3: L1 w12..15 + CRX15, observables, 8th-arriver FC ----------------
// block n = pos12,13,14 (saddr8..10). reg = pos0..3 (saddr12..15), l0..4 = pos4..8 (saddr0..4),
// l5 = pos15 (saddr11), wv = pos9,10,11 (saddr5..7).

__global__ __launch_bounds__(512) void p3(const unsigned* __restrict__ st, const float* __restrict__ P,
                                          float* __restrict__ feats, int* __restrict__ ctr,
                                          const float* __restrict__ fcw, const float* __restrict__ fcb,
                                          float* __restrict__ out) {
  int blk = blockIdx.x;
  int b = blk >> 3, n = blk & 7;
  int t = threadIdx.x, lane = t & 63, wv = t >> 6;
  const float* Pb = P + (size_t)b*PSTR;
  int base = (lane&31) | (wv << 5) | (n << 8) | ((lane>>5) << 11);
  const unsigned* S = st + (size_t)b*DIM + base;
  float sr[16], si[16];
#pragma unroll
  for (int r = 0; r < 16; ++r) { unsigned u = S[r << 12]; sr[r] = bfr(u); si[r] = bfi(u); }

  gsel_reg_pred<3>(sr, si, MP(Pb,1,12,0), MP(Pb,1,12,1), (lane&1)!=0);
  gsel_reg_cc<2,3>(sr, si, MP(Pb,1,13,0), MP(Pb,1,13,1));
  gsel_reg_cc<1,2>(sr, si, MP(Pb,1,14,0), MP(Pb,1,14,1));
  gsel_reg_cc<0,1>(sr, si, MP(Pb,1,15,0), MP(Pb,1,15,1));
  crx_reg_lane<0,5>(sr, si, Pb[576], Pb[577]);

  float tot=0.f, sA=0.f, sB=0.f, sC=0.f, sD=0.f;
#pragma unroll
  for (int r = 0; r < 16; ++r) {
    float p = sr[r]*sr[r] + si[r]*si[r];
    tot += p;
    sA += (r & 1) ? -p : p;   // pos0 -> wire15
    sB += (r & 2) ? -p : p;   // pos1 -> wire14
    sC += (r & 4) ? -p : p;   // pos2 -> wire13
    sD += (r & 8) ? -p : p;   // pos3 -> wire12
  }
  float f[16];
  f[15] = sA; f[14] = sB; f[13] = sC; f[12] = sD;
  f[11] = (lane&1)  ? -tot : tot;   // pos4
  f[10] = (lane&2)  ? -tot : tot;   // pos5
  f[9]  = (lane&4)  ? -tot : tot;   // pos6
  f[8]  = (lane&8)  ? -tot : tot;   // pos7
  f[7]  = (lane&16) ? -tot : tot;   // pos8
  f[0]  = (lane&32) ? -tot : tot;   // pos15
  f[6]  = (wv&1)    ? -tot : tot;   // pos9
  f[5]  = (wv&2)    ? -tot : tot;   // pos10
  f[4]  = (wv&4)    ? -tot : tot;   // pos11
  f[3]  = (n&1)     ? -tot : tot;   // pos12
  f[2]  = (n&2)     ? -tot : tot;   // pos13
  f[1]  = (n&4)     ? -tot : tot;   // pos14
#pragma unroll
  for (int w = 0; w < 16; ++w) {
#pragma unroll
    for (int off = 32; off; off >>= 1) f[w] += __shfl_xor(f[w], off, 64);
  }
  __shared__ float red[8][17];
  if (lane == 0) {
#pragma unroll
    for (int w = 0; w < 16; ++w) red[wv][w] = f[w];
  }
  __syncthreads();
  if (t < 16) {
    float acc = 0.f;
#pragma unroll
    for (int i = 0; i < 8; ++i) acc += red[i][t];
    atomicAdd(&feats[b*16 + t], acc);
  }

  // last block per batch computes FC + log_softmax
  __shared__ int flagS;
  __syncthreads();
  if (t == 0) { __threadfence(); flagS = atomicAdd(&ctr[b], 1); }
  __syncthreads();
  if (flagS == 7) {
    __shared__ float fs[16];
    __shared__ float lg[23];
    if (t < 16) fs[t] = __hip_atomic_load(&feats[b*16 + t], __ATOMIC_RELAXED, __HIP_MEMORY_SCOPE_AGENT);
    __syncthreads();
    if (t < 23) {
      float acc = fcb[t];
#pragma unroll
      for (int w = 0; w < 16; ++w) acc += fs[w] * fcw[t*16 + w];
      lg[t] = acc;
    }
    __syncthreads();
    if (t < 23) {
      float mx = -1e30f;
#pragma unroll
      for (int j = 0; j < 23; ++j) mx = fmaxf(mx, lg[j]);
      float Ssum = 0.f;
#pragma unroll
      for (int j = 0; j < 23; ++j) Ssum += expf(lg[j] - mx);
      out[b*23 + t] = lg[t] - mx - logf(Ssum);
    }
  }
}

extern "C" void kernel_launch(void* const* d_in, const int* in_sizes, int n_in,
                              void* d_out, int out_size, void* d_ws, size_t ws_size,
                              hipStream_t stream) {
  const float* x   = (const float*)d_in[0];
  const float* w0  = (const float*)d_in[1];
  const float* x0  = (const float*)d_in[2];
  const float* w1  = (const float*)d_in[3];
  const float* x1  = (const float*)d_in[4];
  const float* fcw = (const float*)d_in[5];
  const float* fcb = (const float*)d_in[6];
  float* out = (float*)d_out;

  char* ws = (char*)d_ws;
  unsigned* st  = (unsigned*)ws;                                   // 16 MB
  float*  P     = (float*)(ws + (size_t)BATCH * DIM * 4);
  float*  feats = P + (size_t)BATCH * PSTR;
  int*    ctr   = (int*)(feats + BATCH*16);

  pB2<<<1024, 256, 0, stream>>>(st, x, w0, x0, w1, x1, P, feats, ctr);
  p3<<<512, 512, 0, stream>>>(st, P, feats, ctr, fcw, fcb, out);
  (void)in_sizes; (void)n_in; (void)out_size; (void)ws_size;
}